// Round 6
// baseline (528.532 us; speedup 1.0000x reference)
//
#include <hip/hip_runtime.h>

// VQ quantize: N=65536 tokens, D=256, K=1024 codes.
// Round 6: barrier-free vq_score — B fragments read directly from L2 (no LDS
//          staging; codebook is 1MB, L2-resident), lane-contiguous quantize
//          write, tight FLAG_TH (50-sigma) + wider fixup parallelism.

#define D 256
#define K 1024
#define NTOK 65536

// flat float32 output offsets (return-order concat)
#define OFF_Q   ((size_t)1)
#define OFF_CS  ((size_t)1 + (size_t)NTOK * D)     // 16777217
#define OFF_DW  (OFF_CS + K)                        // 16778241
#define OFF_IDX (OFF_DW + (size_t)D * K)            // 17040385
#define OFF_P   (OFF_IDX + NTOK)                    // 17105921

#define FLAG_TH  0.008f
#define FLAG_CAP 8192

typedef __attribute__((ext_vector_type(8))) short short8;
typedef __attribute__((ext_vector_type(16))) float f32x16;

__device__ __forceinline__ unsigned short f2bf(float f) {
  unsigned u = __float_as_uint(f);
  return (unsigned short)((u + 0x7FFFu + ((u >> 16) & 1u)) >> 16);
}
__device__ __forceinline__ float bf2f(unsigned short h) {
  return __uint_as_float(((unsigned)h) << 16);
}

// ---- prep: wT fp32 [K][D]; wBG bf16 hi/lo in per-chunk {hi 8192; lo 8192} ----
// frag idx for (k,d): s=d>>4, hi=(d>>3)&1, col=k&31, b=d&7 ->
//   ((s*2+hi)*32 + col)*8 + b  within 8192; chunk = k>>5
// per (s, wave): lane=hi*32+col reads shorts [chunk*16384 + s*512 + lane*8, +8)
__global__ __launch_bounds__(256) void prep_w(const float* __restrict__ w,
                                              float* __restrict__ wT,
                                              unsigned short* __restrict__ wBG) {
  __shared__ float tile[32][33];
  const int k0 = blockIdx.x * 32, d0 = blockIdx.y * 32;
  const int tx = threadIdx.x, ty = threadIdx.y;  // 32x8
#pragma unroll
  for (int j = 0; j < 4; ++j) {
    const int r = ty + j * 8;
    tile[r][tx] = w[(size_t)(d0 + r) * K + k0 + tx];
  }
  __syncthreads();
#pragma unroll
  for (int j = 0; j < 4; ++j) {
    const int r = ty + j * 8;
    const int k = k0 + r, d = d0 + tx;
    const float v = tile[tx][r];
    wT[(size_t)k * D + d] = v;
    const unsigned short h = f2bf(v);
    const unsigned short l = f2bf(v - bf2f(h));
    const size_t frag = (size_t)(((d >> 4) * 2 + ((d >> 3) & 1)) * 32 + (k & 31)) * 8 +
                        (d & 7);
    const size_t base = (size_t)(k >> 5) * 16384;
    wBG[base + frag] = h;
    wBG[base + 8192 + frag] = l;
  }
}

__global__ __launch_bounds__(256) void wsq_kernel(const float* __restrict__ wT,
                                                  float* __restrict__ wsq) {
  const int wave = threadIdx.x >> 6, lane = threadIdx.x & 63;
  const int k = blockIdx.x * 4 + wave;
  const float4 v = *(const float4*)(wT + (size_t)k * D + lane * 4);
  float s = v.x * v.x + v.y * v.y + v.z * v.z + v.w * v.w;
#pragma unroll
  for (int m = 1; m < 64; m <<= 1) s += __shfl_xor(s, m);
  if (lane == 0) wsq[k] = s;
}

// ---- bf16x2 screening GEMM, barrier-free: B direct from L2 ----
// block = 256 thr (4 waves x 32 tokens = 128 tokens), grid 512
__global__ __launch_bounds__(256, 2) void vq_score(
    const float* __restrict__ x, const unsigned short* __restrict__ wBG,
    const float* __restrict__ wsq, const float* __restrict__ wT,
    float* __restrict__ out, int* __restrict__ idxInt, int* __restrict__ countsInt,
    int* __restrict__ flagCnt, int* __restrict__ flagged) {
  __shared__ float swsq[K];

  const int tid = threadIdx.x;
#pragma unroll
  for (int j = 0; j < 4; ++j) swsq[tid + j * 256] = wsq[tid + j * 256];

  const int wv = tid >> 6, lane = tid & 63;
  const int col = lane & 31, hi = lane >> 5;
  const int rowG = blockIdx.x * 128 + wv * 32 + col;

  // A fragments (token rows), hi/lo split
  short8 ah[16], al[16];
  {
    const float* xr = x + (size_t)rowG * D + hi * 8;
#pragma unroll
    for (int s = 0; s < 16; ++s) {
      const float4 f0 = *(const float4*)(xr + s * 16);
      const float4 f1 = *(const float4*)(xr + s * 16 + 4);
      const float fv[8] = {f0.x, f0.y, f0.z, f0.w, f1.x, f1.y, f1.z, f1.w};
      short8 a, b;
#pragma unroll
      for (int e = 0; e < 8; ++e) {
        const unsigned short h = f2bf(fv[e]);
        a[e] = (short)h;
        b[e] = (short)f2bf(fv[e] - bf2f(h));
      }
      ah[s] = a;
      al[s] = b;
    }
  }

  float s1[16], s2[16];
  int i1[16];
#pragma unroll
  for (int r = 0; r < 16; ++r) { s1[r] = -3.4e38f; s2[r] = -3.4e38f; i1[r] = 0; }

  __syncthreads();  // swsq resident (only barrier in the kernel)

  for (int chunk = 0; chunk < 32; ++chunk) {
    // B fragments straight from global (L2-resident 1MB codebook)
    const short8* bhG = (const short8*)(wBG + (size_t)chunk * 16384) + lane;
    const short8* blG = bhG + 1024;  // +8192 shorts

    f32x16 ahh, ahl, alh;
#pragma unroll
    for (int r = 0; r < 16; ++r) { ahh[r] = 0.f; ahl[r] = 0.f; alh[r] = 0.f; }
#pragma unroll
    for (int s = 0; s < 16; ++s) {
      const short8 bh = bhG[s * 64];   // wave reads contiguous 1KB per s
      const short8 bl = blG[s * 64];
      ahh = __builtin_amdgcn_mfma_f32_32x32x16_bf16(ah[s], bh, ahh, 0, 0, 0);
      ahl = __builtin_amdgcn_mfma_f32_32x32x16_bf16(ah[s], bl, ahl, 0, 0, 0);
      alh = __builtin_amdgcn_mfma_f32_32x32x16_bf16(al[s], bh, alh, 0, 0, 0);
    }

    const int cc = chunk * 32 + col;
    const float wq = swsq[cc];
#pragma unroll
    for (int r = 0; r < 16; ++r) {
      const float sc = fmaf(2.f, ahh[r] + ahl[r] + alh[r], -wq);
      const bool gt = sc > s1[r];
      s2[r] = fmaxf(s2[r], gt ? s1[r] : sc);
      if (gt) { s1[r] = sc; i1[r] = cc; }
    }
  }

  // cross-lane top-2 merge (masks 1..16 keep hi fixed -> same token set)
#pragma unroll
  for (int m = 1; m <= 16; m <<= 1) {
#pragma unroll
    for (int r = 0; r < 16; ++r) {
      const float os1 = __shfl_xor(s1[r], m);
      const int   oi1 = __shfl_xor(i1[r], m);
      const float os2 = __shfl_xor(s2[r], m);
      const bool take = (os1 > s1[r]) || (os1 == s1[r] && oi1 < i1[r]);
      const float loser = take ? s1[r] : os1;
      if (take) { s1[r] = os1; i1[r] = oi1; }
      s2[r] = fmaxf(fmaxf(s2[r], os2), loser);
    }
  }

  const size_t tb = (size_t)blockIdx.x * 128 + wv * 32;

  if (col == 0) {
#pragma unroll
    for (int r = 0; r < 16; ++r) {
      const int row = (r & 3) + 8 * (r >> 2) + 4 * hi;  // C/D row map (m74/m101)
      const size_t g = tb + row;
      idxInt[g] = i1[r];
      out[OFF_IDX + g] = (float)i1[r];
      atomicAdd(countsInt + i1[r], 1);
      if (s1[r] - s2[r] < FLAG_TH) {
        const int slot = atomicAdd(flagCnt, 1);
        if (slot < FLAG_CAP) flagged[slot] = (int)g;
      }
    }
  }

  // fused quantize write: half-wave per row, lane-contiguous (coalesced)
  const int l32 = lane & 31;
#pragma unroll
  for (int r = 0; r < 16; ++r) {
    const int row = (r & 3) + 8 * (r >> 2) + 4 * hi;
    const size_t t = tb + row;
    const int k = i1[r];  // uniform within half-wave
    const float* wrow = wT + (size_t)k * D;
    float* od = out + OFF_Q + t * D;  // base misaligned by 1 float -> scalar
#pragma unroll
    for (int c = 0; c < 8; ++c) {
      const int e = c * 32 + l32;     // 128B contiguous per half-wave per instr
      od[e] = wrow[e];
    }
  }
}

// ---- exact fp32 rescan: private keys per (slot, chunk), no contention ----
// grid 2048 = 32 chunks x 64 slot-groups
__global__ __launch_bounds__(256) void vq_fixup(
    const float* __restrict__ x, const float* __restrict__ wT,
    const float* __restrict__ wsq, const int* __restrict__ flagCnt,
    const int* __restrict__ flagged, unsigned long long* __restrict__ keyBuf) {
  __shared__ float ws32[32 * 264];
  __shared__ float xs[D];
  __shared__ unsigned long long wred[4];
  const int tid = threadIdx.x;
  const int cc = blockIdx.x & 31, j0 = blockIdx.x >> 5;  // chunk, slot-group
#pragma unroll
  for (int r = 0; r < 32; ++r)
    ws32[r * 264 + tid] = wT[(size_t)(cc * 32 + r) * D + tid];
  int F = *flagCnt;
  if (F > FLAG_CAP) F = FLAG_CAP;
  const int ci = tid >> 3, dg = tid & 7, c = cc * 32 + ci;
  const float wq = wsq[c];

  for (int slot = j0; slot < F; slot += 64) {
    const int t = flagged[slot];
    __syncthreads();
    xs[tid] = x[(size_t)t * D + tid];
    __syncthreads();
    float dot = 0.f;
#pragma unroll
    for (int i = 0; i < 32; ++i)
      dot = fmaf(xs[dg + 8 * i], ws32[ci * 264 + dg + 8 * i], dot);
    dot += __shfl_xor(dot, 1);
    dot += __shfl_xor(dot, 2);
    dot += __shfl_xor(dot, 4);
    unsigned long long key = 0ull;
    if (dg == 0) {
      const float sc = fmaf(2.f, dot, -wq);
      unsigned u = __float_as_uint(sc);
      u = (u & 0x80000000u) ? ~u : (u | 0x80000000u);
      key = ((unsigned long long)u << 32) | (unsigned)(1023 - c);
    }
#pragma unroll
    for (int m = 8; m <= 32; m <<= 1) {
      const unsigned long long o = __shfl_xor(key, m);
      if (o > key) key = o;
    }
    if ((tid & 63) == 0) wred[tid >> 6] = key;
    __syncthreads();
    if (tid == 0) {
      unsigned long long b = wred[0];
      if (wred[1] > b) b = wred[1];
      if (wred[2] > b) b = wred[2];
      if (wred[3] > b) b = wred[3];
      keyBuf[(size_t)slot * 32 + cc] = b;
    }
  }
}

// ---- finalize flagged tokens: fix idx, counts, and quantize row ----
__global__ __launch_bounds__(256) void vq_fixfin(
    const int* __restrict__ flagCnt, const int* __restrict__ flagged,
    const unsigned long long* __restrict__ keyBuf, int* __restrict__ idxInt,
    int* __restrict__ countsInt, const float* __restrict__ wT,
    float* __restrict__ out) {
  int F = *flagCnt;
  if (F > FLAG_CAP) F = FLAG_CAP;
  const int wv = threadIdx.x >> 6, lane = threadIdx.x & 63;
  for (int slot = blockIdx.x * 4 + wv; slot < F; slot += 64) {
    const int t = flagged[slot];
    unsigned long long key = (lane < 32) ? keyBuf[(size_t)slot * 32 + lane] : 0ull;
#pragma unroll
    for (int m = 1; m <= 32; m <<= 1) {
      const unsigned long long o = __shfl_xor(key, m);
      if (o > key) key = o;
    }
    const int c = 1023 - (int)(key & 0xFFFFFFFFull);
    const int old = idxInt[t];
    if (c != old) {
      if (lane == 0) {
        idxInt[t] = c;
        out[OFF_IDX + t] = (float)c;
        atomicAdd(countsInt + old, -1);
        atomicAdd(countsInt + c, 1);
      }
      const float4 q = *(const float4*)(wT + (size_t)c * D + lane * 4);
      float* od = out + OFF_Q + (size_t)t * D + lane * 4;
      od[0] = q.x; od[1] = q.y; od[2] = q.z; od[3] = q.w;
    }
  }
}

// ---- scan: counts -> cluster-size output, bucket starts, cursors ----
__global__ __launch_bounds__(1024) void vq_scan(const int* __restrict__ countsInt,
                                                int* __restrict__ bucketStart,
                                                int* __restrict__ cursorInt,
                                                float* __restrict__ out) {
  __shared__ int sc[1024];
  const int tid = threadIdx.x;
  const int c = countsInt[tid];
  out[OFF_CS + tid] = (float)c;
  sc[tid] = c;
  __syncthreads();
  for (int off = 1; off < 1024; off <<= 1) {
    int v = 0;
    if (tid >= off) v = sc[tid - off];
    __syncthreads();
    if (tid >= off) sc[tid] += v;
    __syncthreads();
  }
  bucketStart[tid] = sc[tid] - c;  // exclusive
  cursorInt[tid] = 0;
}

__global__ __launch_bounds__(256) void vq_scatter(const int* __restrict__ idxInt,
                                                  const int* __restrict__ bucketStart,
                                                  int* __restrict__ cursorInt,
                                                  int* __restrict__ sortedTok) {
  const int t = blockIdx.x * 256 + threadIdx.x;
  const int k = idxInt[t];
  const int pos = atomicAdd(cursorInt + k, 1);
  sortedTok[bucketStart[k] + pos] = t;
}

// ---- dw + loss over sorted tokens: 16 positions per wave, flush on change ----
__global__ __launch_bounds__(256) void vq_dwloss(
    const float* __restrict__ x, const float* __restrict__ wT,
    const int* __restrict__ idxInt, const int* __restrict__ sortedTok,
    float* __restrict__ dwT, float* __restrict__ lossAcc) {
  __shared__ float sRed[4];
  const int tid = threadIdx.x, wv = tid >> 6, lane = tid & 63;
  const int g = blockIdx.x * 4 + wv;   // 4096 waves
  const int p0 = g * 16;
  const int tk = sortedTok[p0 + (lane & 15)];
  const int kk = idxInt[tk];

  int kcur = -1;
  float4 acc = {0.f, 0.f, 0.f, 0.f};
  float4 wv4 = {0.f, 0.f, 0.f, 0.f};
  float lp = 0.f;
#pragma unroll
  for (int i = 0; i < 16; ++i) {
    const int t = __shfl(tk, i);
    const int k = __shfl(kk, i);
    if (k != kcur) {
      if (kcur >= 0) {
        float* dr = dwT + (size_t)kcur * D + lane * 4;
        atomicAdd(dr + 0, acc.x); atomicAdd(dr + 1, acc.y);
        atomicAdd(dr + 2, acc.z); atomicAdd(dr + 3, acc.w);
      }
      acc = {0.f, 0.f, 0.f, 0.f};
      wv4 = *(const float4*)(wT + (size_t)k * D + lane * 4);
      kcur = k;
    }
    const float4 xv = *(const float4*)(x + (size_t)t * D + lane * 4);
    acc.x += xv.x; acc.y += xv.y; acc.z += xv.z; acc.w += xv.w;
    const float dx = wv4.x - xv.x, dy = wv4.y - xv.y;
    const float dz = wv4.z - xv.z, dw = wv4.w - xv.w;
    lp = fmaf(dx, dx, lp); lp = fmaf(dy, dy, lp);
    lp = fmaf(dz, dz, lp); lp = fmaf(dw, dw, lp);
  }
  {
    float* dr = dwT + (size_t)kcur * D + lane * 4;
    atomicAdd(dr + 0, acc.x); atomicAdd(dr + 1, acc.y);
    atomicAdd(dr + 2, acc.z); atomicAdd(dr + 3, acc.w);
  }
#pragma unroll
  for (int m = 1; m < 64; m <<= 1) lp += __shfl_xor(lp, m);
  if (lane == 0) sRed[wv] = lp;
  __syncthreads();
  if (tid == 0) atomicAdd(lossAcc, sRed[0] + sRed[1] + sRed[2] + sRed[3]);
}

__global__ __launch_bounds__(256) void transpose_dw(const float* __restrict__ dwT,
                                                    float* __restrict__ out) {
  __shared__ float tile[32][33];
  const int d0 = blockIdx.x * 32, k0 = blockIdx.y * 32;
  const int tx = threadIdx.x, ty = threadIdx.y;  // 32x8
#pragma unroll
  for (int j = 0; j < 4; ++j) {
    const int r = ty + j * 8;
    tile[r][tx] = dwT[(size_t)(k0 + r) * D + d0 + tx];
  }
  __syncthreads();
#pragma unroll
  for (int j = 0; j < 4; ++j) {
    const int r = ty + j * 8;
    out[OFF_DW + (size_t)(d0 + r) * K + k0 + tx] = tile[tx][r];
  }
}

__global__ __launch_bounds__(1024) void finalize_kernel(const float* __restrict__ lossAcc,
                                                        float* __restrict__ out) {
  __shared__ float red[16];
  const int tid = threadIdx.x;
  const float c = out[OFF_CS + tid];
  const float avg = c * (1.0f / (float)NTOK);
  float term = avg * logf(avg + 1e-10f);
#pragma unroll
  for (int m = 1; m < 64; m <<= 1) term += __shfl_xor(term, m);
  const int wave = tid >> 6, lane = tid & 63;
  if (lane == 0) red[wave] = term;
  __syncthreads();
  if (tid == 0) {
    float s = 0.f;
#pragma unroll
    for (int i = 0; i < 16; ++i) s += red[i];
    out[OFF_P] = expf(-s);
    out[0] = lossAcc[0] * (1.0f / ((float)NTOK * (float)D));
  }
}

extern "C" void kernel_launch(void* const* d_in, const int* in_sizes, int n_in,
                              void* d_out, int out_size, void* d_ws, size_t ws_size,
                              hipStream_t stream) {
  const float* x = (const float*)d_in[0];
  const float* w = (const float*)d_in[1];
  float* out = (float*)d_out;
  char* wsb = (char*)d_ws;

  // ws layout (bytes)
  float* lossAcc     = (float*)(wsb + 0);
  int*   flagCnt     = (int*)(wsb + 4);
  int*   countsInt   = (int*)(wsb + 4096);
  int*   bucketStart = (int*)(wsb + 8192);
  int*   cursorInt   = (int*)(wsb + 12288);
  float* wsq         = (float*)(wsb + 16384);
  int*   idxInt      = (int*)(wsb + 20480);                        // 256 KB
  int*   sortedTok   = (int*)(wsb + 282624);                       // 256 KB
  int*   flagged     = (int*)(wsb + 544768);                       // 32 KB
  unsigned long long* keyBuf = (unsigned long long*)(wsb + 577536);  // 2 MB
  float* wT          = (float*)(wsb + 2674688);                    // 1 MB
  unsigned short* wBG = (unsigned short*)(wsb + 3723264);          // 1 MB
  float* dwT         = (float*)(wsb + 4771840);                    // 1 MB

  // zero accumulators (d_ws is 0xAA-poisoned before every timed call)
  hipMemsetAsync(wsb, 0, 20480, stream);
  hipMemsetAsync(dwT, 0, sizeof(float) * (size_t)K * D, stream);

  prep_w<<<dim3(K / 32, D / 32), dim3(32, 8), 0, stream>>>(w, wT, wBG);
  wsq_kernel<<<dim3(K / 4), dim3(256), 0, stream>>>(wT, wsq);
  vq_score<<<dim3(NTOK / 128), dim3(256), 0, stream>>>(
      x, wBG, wsq, wT, out, idxInt, countsInt, flagCnt, flagged);
  vq_fixup<<<dim3(2048), dim3(256), 0, stream>>>(x, wT, wsq, flagCnt, flagged, keyBuf);
  vq_fixfin<<<dim3(16), dim3(256), 0, stream>>>(flagCnt, flagged, keyBuf, idxInt,
                                                countsInt, wT, out);
  vq_scan<<<dim3(1), dim3(1024), 0, stream>>>(countsInt, bucketStart, cursorInt, out);
  vq_scatter<<<dim3(NTOK / 256), dim3(256), 0, stream>>>(idxInt, bucketStart,
                                                         cursorInt, sortedTok);
  vq_dwloss<<<dim3(1024), dim3(256), 0, stream>>>(x, wT, idxInt, sortedTok,
                                                  dwT, lossAcc);
  transpose_dw<<<dim3(D / 32, K / 32), dim3(32, 8), 0, stream>>>(dwT, out);
  finalize_kernel<<<dim3(1), dim3(1024), 0, stream>>>(lossAcc, out);
}